// Round 16
// baseline (382.303 us; speedup 1.0000x reference)
//
#include <hip/hip_runtime.h>
#include <hip/hip_bf16.h>
#include <math.h>

constexpr int KN  = 100;            // K (multi_factor * top_k)
constexpr int DE  = 64;             // embedding dim
constexpr int CAT = 2 * KN * DE;    // 12800
constexpr int HID = 128;
constexpr int CHUNK = 2048;         // pipeline chunk (4 chunks, dbuf'd)
constexpr int KSPLIT = 8;
constexpr int KSEG = CAT / KSPLIT;  // 1600
constexpr int MLP_BK = 32;

typedef __bf16          bf16x8   __attribute__((ext_vector_type(8)));
typedef float           f32x4    __attribute__((ext_vector_type(4)));
typedef unsigned short  ushort8v __attribute__((ext_vector_type(8)));
typedef unsigned short  ushort4v __attribute__((ext_vector_type(4)));

static __device__ __forceinline__ unsigned short f2bf(float f) {
    __hip_bfloat16 h = __float2bfloat16(f);
    return *reinterpret_cast<unsigned short*>(&h);
}

static __device__ __forceinline__ bf16x8 mk_frag(ushort4v lo, ushort4v hi) {
    union { ushort8v u; bf16x8 b; } c;
    c.u = (ushort8v){ lo[0], lo[1], lo[2], lo[3], hi[0], hi[1], hi[2], hi[3] };
    return c.b;
}

// ---------------------------------------------------------------------------
// prep: 4 fp32->bf16 table conversions in one launch
// ---------------------------------------------------------------------------
__global__ __launch_bounds__(256) void cvt4(
    const float* __restrict__ a0, unsigned short* __restrict__ o0, int n0,
    const float* __restrict__ a1, unsigned short* __restrict__ o1, int n1,
    const float* __restrict__ a2, unsigned short* __restrict__ o2, int n2,
    const float* __restrict__ a3, unsigned short* __restrict__ o3, int n3)
{
    const float* in; unsigned short* out; int n4;
    switch (blockIdx.y) {
        case 0:  in = a0; out = o0; n4 = n0; break;
        case 1:  in = a1; out = o1; n4 = n1; break;
        case 2:  in = a2; out = o2; n4 = n2; break;
        default: in = a3; out = o3; n4 = n3; break;
    }
    for (int i = blockIdx.x * 256 + threadIdx.x; i < n4; i += gridDim.x * 256) {
        float4 v = ((const float4*)in)[i];
        ushort4v o = { f2bf(v.x), f2bf(v.y), f2bf(v.z), f2bf(v.w) };
        ((ushort4v*)out)[i] = o;
    }
}

// ---------------------------------------------------------------------------
// prep: w1t[n][k] = bf16(W1[k][n])
// ---------------------------------------------------------------------------
__global__ __launch_bounds__(256) void prep_w1t(
    const float* __restrict__ W1, unsigned short* __restrict__ w1t)
{
    __shared__ unsigned short T[HID][72];
    const int t  = threadIdx.x;
    const int k0 = blockIdx.x * 64;

    for (int idx = t; idx < 64 * HID; idx += 256) {
        int kk = idx >> 7, n = idx & 127;
        T[n][kk] = f2bf(W1[(size_t)(k0 + kk) * HID + n]);
    }
    __syncthreads();
    for (int idx = t; idx < HID * 16; idx += 256) {
        int n = idx >> 4, c4 = idx & 15;
        *(ushort4v*)&w1t[(size_t)n * CAT + k0 + c4 * 4] =
            *(const ushort4v*)&T[n][c4 * 4];
    }
}

// ===========================================================================
// Role bodies for the fused pipeline kernel.
// ===========================================================================

// einsum: identical math to r15 (proven).  ET + nb live in smem.
__device__ __forceinline__ void einsum_body(
    unsigned char* smem,
    const int* __restrict__ idxs, const int* __restrict__ nbt,
    const unsigned short* __restrict__ scr, const unsigned short* __restrict__ emb,
    unsigned short* __restrict__ xr, int b)
{
    typedef unsigned short (*ET_t)[136];
    ET_t ET = (ET_t)smem;                               // [64][136] = 17408 B
    int* nb = (int*)(smem + 64 * 136 * 2);              // 100 ints

    const int t = threadIdx.x;
    const ushort4v z4 = {0, 0, 0, 0};

    const int center = idxs[b];
    if (t < KN) nb[t] = nbt[(size_t)center * KN + t];

    for (int idx = t; idx < 64 * 7; idx += 256) {
        int r = idx / 7, c = idx - r * 7;
        *(ushort4v*)&ET[r][100 + c * 4] = z4;
    }
    __syncthreads();                                    // nb ready

    for (int idx = t; idx < 25 * 16; idx += 256) {
        int d4 = idx / 25, j0 = idx - d4 * 25;
        ushort4v v0 = *(const ushort4v*)(emb + (size_t)nb[j0 * 4 + 0] * DE + d4 * 4);
        ushort4v v1 = *(const ushort4v*)(emb + (size_t)nb[j0 * 4 + 1] * DE + d4 * 4);
        ushort4v v2 = *(const ushort4v*)(emb + (size_t)nb[j0 * 4 + 2] * DE + d4 * 4);
        ushort4v v3 = *(const ushort4v*)(emb + (size_t)nb[j0 * 4 + 3] * DE + d4 * 4);
        ushort4v o0 = { v0[0], v1[0], v2[0], v3[0] };
        ushort4v o1 = { v0[1], v1[1], v2[1], v3[1] };
        ushort4v o2 = { v0[2], v1[2], v2[2], v3[2] };
        ushort4v o3 = { v0[3], v1[3], v2[3], v3[3] };
        *(ushort4v*)&ET[d4 * 4 + 0][j0 * 4] = o0;
        *(ushort4v*)&ET[d4 * 4 + 1][j0 * 4] = o1;
        *(ushort4v*)&ET[d4 * 4 + 2][j0 * 4] = o2;
        *(ushort4v*)&ET[d4 * 4 + 3][j0 * 4] = o3;
    }
    __syncthreads();

    const int w  = t >> 6;
    const int l  = t & 63;
    const int cl = l & 15;
    const int rg = l >> 4;

    const unsigned short* srow[7];
    #pragma unroll
    for (int mt = 0; mt < 7; ++mt) {
        int kr = mt * 16 + cl;
        if (kr > KN - 1) kr = KN - 1;
        srow[mt] = scr + (size_t)nb[kr] * KN;
    }

    f32x4 acc[7];
    #pragma unroll
    for (int m = 0; m < 7; ++m) acc[m] = (f32x4){0.f, 0.f, 0.f, 0.f};

    #pragma unroll
    for (int ks = 0; ks < 4; ++ks) {
        const int k0 = ks * 32 + rg * 8;
        bf16x8 bfrag = *(const bf16x8*)&ET[w * 16 + cl][k0];
        #pragma unroll
        for (int mt = 0; mt < 7; ++mt) {
            ushort4v lo, hi;
            if (ks < 3) {
                lo = *(const ushort4v*)(srow[mt] + k0);
                hi = *(const ushort4v*)(srow[mt] + k0 + 4);
            } else if (rg == 0) {
                lo = *(const ushort4v*)(srow[mt] + 96);
                hi = z4;
            } else {
                lo = z4; hi = z4;
            }
            bf16x8 afrag = mk_frag(lo, hi);
            acc[mt] = __builtin_amdgcn_mfma_f32_16x16x32_bf16(afrag, bfrag, acc[mt], 0, 0, 0);
        }
    }
    __syncthreads();

    unsigned short* X = (unsigned short*)smem;          // reuse as D-bounce
    #pragma unroll
    for (int mt = 0; mt < 7; ++mt) {
        #pragma unroll
        for (int rr = 0; rr < 4; ++rr) {
            int k = mt * 16 + rg * 4 + rr;
            if (k < KN) X[k * 72 + w * 16 + cl] = f2bf(acc[mt][rr]);
        }
    }
    __syncthreads();

    for (int idx = t; idx < KN * 8; idx += 256) {
        int r = idx >> 3, c8 = idx & 7;
        __builtin_nontemporal_store(*(const ushort8v*)&X[r * 72 + c8 * 8],
                                    (ushort8v*)&xr[r * DE + c8 * 8]);
    }
}

// mlp: r15-proven structure re-tiled to MLP_BK=32 so LDS fits 30.7 KB
// (A[2][64][40] + Bt[2][128][40]).  Same K accumulation order as r15.
__device__ __forceinline__ void mlp_body(
    unsigned char* smem,
    const unsigned short* __restrict__ xb, const unsigned short* __restrict__ w1t,
    float* __restrict__ hp, int rows, int mb, int mrb)
{
    typedef unsigned short (*A_t)[64][40];
    typedef unsigned short (*B_t)[HID][40];
    A_t A  = (A_t)smem;                                  // 10240 B
    B_t Bt = (B_t)(smem + 2 * 64 * 40 * 2);              // 20480 B

    const int t  = threadIdx.x;
    const int w  = t >> 6;
    const int l  = t & 63;
    const int cl = l & 15;
    const int rg = l >> 4;
    const int bx = mb % mrb;
    const int q  = mb / mrb;
    const int row0  = bx * 64;
    const int kbase = q * KSEG;

    auto stage = [&](int buf, int kb) {
        {   // A: 64 rows x 4 16B-chunks = 256, 1/thread
            int r = t >> 2, c = t & 3;
            *(ushort8v*)&A[buf][r][c * 8] = __builtin_nontemporal_load(
                (const ushort8v*)&xb[(size_t)(row0 + r) * CAT + kbase + kb + c * 8]);
        }
        #pragma unroll
        for (int i = 0; i < 2; ++i) {   // Bt: 128 rows x 4 chunks = 512, 2/thread
            int c2 = t + i * 256;
            int n = c2 >> 2, c = c2 & 3;
            *(ushort8v*)&Bt[buf][n][c * 8] =
                *(const ushort8v*)&w1t[(size_t)n * CAT + kbase + kb + c * 8];
        }
    };

    f32x4 acc[4][2];
    #pragma unroll
    for (int mt = 0; mt < 4; ++mt)
        #pragma unroll
        for (int nt = 0; nt < 2; ++nt)
            acc[mt][nt] = (f32x4){0.f, 0.f, 0.f, 0.f};

    stage(0, 0);
    __syncthreads();

    constexpr int NS = KSEG / MLP_BK;   // 50
    for (int s = 0; s < NS; ++s) {
        const int cur = s & 1;
        if (s + 1 < NS) stage(cur ^ 1, (s + 1) * MLP_BK);   // issue loads FIRST
        const int kcol = rg * 8;
        bf16x8 bv0 = *(const bf16x8*)&Bt[cur][w * 32 + cl][kcol];
        bf16x8 bv1 = *(const bf16x8*)&Bt[cur][w * 32 + 16 + cl][kcol];
        #pragma unroll
        for (int mt = 0; mt < 4; ++mt) {
            bf16x8 a = *(const bf16x8*)&A[cur][mt * 16 + cl][kcol];
            acc[mt][0] = __builtin_amdgcn_mfma_f32_16x16x32_bf16(a, bv0, acc[mt][0], 0, 0, 0);
            acc[mt][1] = __builtin_amdgcn_mfma_f32_16x16x32_bf16(a, bv1, acc[mt][1], 0, 0, 0);
        }
        __syncthreads();
    }

    #pragma unroll
    for (int mt = 0; mt < 4; ++mt) {
        #pragma unroll
        for (int nt = 0; nt < 2; ++nt) {
            #pragma unroll
            for (int r = 0; r < 4; ++r) {
                size_t row = (size_t)row0 + mt * 16 + rg * 4 + r;
                __builtin_nontemporal_store(acc[mt][nt][r],
                    &hp[((size_t)q * rows + row) * HID + w * 32 + nt * 16 + cl]);
            }
        }
    }
}

// combine: h = relu(sum_{q<8} hp + b1); o = relu(h.W2 + b2); sigmoid.
__device__ __forceinline__ void combine_body(
    unsigned char* smem,
    const float* __restrict__ hp, const float* __restrict__ b1,
    const float* __restrict__ W2, const float* __restrict__ b2,
    float* __restrict__ out, int rows, int cb)
{
    float* red = (float*)smem;
    const int t    = threadIdx.x;
    const int w    = t >> 6;
    const int l    = t & 63;
    const int rsel = w >> 1;
    const int col  = (w & 1) * 64 + l;
    const size_t row = (size_t)cb * 2 + rsel;
    const size_t qs  = (size_t)rows * HID;

    const float* hpr = hp + row * HID + col;
    float v = b1[col];
    #pragma unroll
    for (int j = 0; j < KSPLIT; ++j)
        v += __builtin_nontemporal_load(hpr + j * qs);
    float p = fmaxf(v, 0.f) * W2[col];
    p += __shfl_xor(p, 1,  64);
    p += __shfl_xor(p, 2,  64);
    p += __shfl_xor(p, 4,  64);
    p += __shfl_xor(p, 8,  64);
    p += __shfl_xor(p, 16, 64);
    p += __shfl_xor(p, 32, 64);
    if (l == 0) red[w] = p;
    __syncthreads();
    if (t < 2) {
        float o = red[2 * t] + red[2 * t + 1] + b2[0];
        o = fmaxf(o, 0.f);
        out[cb * 2 + t] = 1.f / (1.f + expf(-o));
    }
}

// ---------------------------------------------------------------------------
// Fused pipeline step: [combine(k-2) | mlp(k-1) | einsum(k)] in one launch.
// Roles touch disjoint buffers (xb/hp double-buffered); cross-chunk deps are
// enforced by stream order between launches.  combine/mlp blocks get LOW ids
// (early residency) so they overlap the einsum majority from t=0.
// ---------------------------------------------------------------------------
__global__ __launch_bounds__(256) void pipe_step(
    const int* __restrict__ u_idx, const int* __restrict__ i_idx,
    const int* __restrict__ u_nbt, const int* __restrict__ i_nbt,
    const unsigned short* __restrict__ u_scr, const unsigned short* __restrict__ i_scr,
    const unsigned short* __restrict__ u_emb, const unsigned short* __restrict__ i_emb,
    unsigned short* __restrict__ e_xb, int e_b0,
    const unsigned short* __restrict__ m_xb, const unsigned short* __restrict__ w1t,
    float* __restrict__ m_hp, int m_rows, int m_nblk,
    const float* __restrict__ c_hp, const float* __restrict__ b1,
    const float* __restrict__ W2, const float* __restrict__ b2,
    float* __restrict__ c_out, int c_rows, int c_nblk)
{
    __shared__ __align__(16) unsigned char smem[2 * 64 * 40 * 2 + 2 * HID * 40 * 2]; // 30720

    int bid = blockIdx.x;
    if (bid < c_nblk) {
        combine_body(smem, c_hp, b1, W2, b2, c_out, c_rows, bid);
        return;
    }
    bid -= c_nblk;
    if (bid < m_nblk) {
        mlp_body(smem, m_xb, w1t, m_hp, m_rows, bid, m_rows / 64);
        return;
    }
    bid -= m_nblk;
    const int row  = bid >> 1;
    const int side = bid & 1;
    einsum_body(smem,
                side ? i_idx : u_idx, side ? i_nbt : u_nbt,
                side ? i_scr : u_scr, side ? i_emb : u_emb,
                e_xb + (size_t)row * CAT + side * (KN * DE),
                e_b0 + row);
}

// ---------------------------------------------------------------------------
extern "C" void kernel_launch(void* const* d_in, const int* in_sizes, int n_in,
                              void* d_out, int out_size, void* d_ws, size_t ws_size,
                              hipStream_t stream)
{
    const int*   user_idxs = (const int*)d_in[0];
    const int*   item_idxs = (const int*)d_in[1];
    const int*   user_nbt  = (const int*)d_in[2];
    const int*   item_nbt  = (const int*)d_in[3];
    const float* user_scr  = (const float*)d_in[4];
    const float* item_scr  = (const float*)d_in[5];
    const float* user_emb  = (const float*)d_in[6];
    const float* item_emb  = (const float*)d_in[7];
    const float* W1        = (const float*)d_in[8];
    const float* b1        = (const float*)d_in[9];
    const float* W2        = (const float*)d_in[10];
    const float* b2        = (const float*)d_in[11];
    float*       out       = (float*)d_out;

    const int B = in_sizes[0];      // 8192
    const int C = (B + CHUNK - 1) / CHUNK;   // 4

    // ws: [w1t 3.3][tables 49.2][hp x2 16.8][xb x2 105] = 174 MB
    char* p = (char*)d_ws;
    unsigned short* w1t   = (unsigned short*)p;  p += (size_t)HID * CAT * 2;
    unsigned short* us_bf = (unsigned short*)p;  p += (size_t)in_sizes[4] * 2;
    unsigned short* is_bf = (unsigned short*)p;  p += (size_t)in_sizes[5] * 2;
    unsigned short* ue_bf = (unsigned short*)p;  p += (size_t)in_sizes[6] * 2;
    unsigned short* ie_bf = (unsigned short*)p;  p += (size_t)in_sizes[7] * 2;
    float*          hpb[2];
    hpb[0] = (float*)p;  p += (size_t)KSPLIT * CHUNK * HID * 4;
    hpb[1] = (float*)p;  p += (size_t)KSPLIT * CHUNK * HID * 4;
    unsigned short* xbuf[2];
    xbuf[0] = (unsigned short*)p;  p += (size_t)CHUNK * CAT * 2;
    xbuf[1] = (unsigned short*)p;

    prep_w1t<<<CAT / 64, 256, 0, stream>>>(W1, w1t);
    cvt4<<<dim3(512, 4), 256, 0, stream>>>(
        user_scr, us_bf, in_sizes[4] / 4,
        item_scr, is_bf, in_sizes[5] / 4,
        user_emb, ue_bf, in_sizes[6] / 4,
        item_emb, ie_bf, in_sizes[7] / 4);

    // software pipeline: launch k runs einsum(k) + mlp(k-1) + combine(k-2)
    for (int k = 0; k <= C + 1; ++k) {
        int e_rows = 0, m_rows = 0, c_rows = 0;
        if (k < C) { e_rows = B - k * CHUNK; if (e_rows > CHUNK) e_rows = CHUNK; }
        int m_c = k - 1;
        if (m_c >= 0 && m_c < C) { m_rows = B - m_c * CHUNK; if (m_rows > CHUNK) m_rows = CHUNK; }
        int c_c = k - 2;
        if (c_c >= 0 && c_c < C) { c_rows = B - c_c * CHUNK; if (c_rows > CHUNK) c_rows = CHUNK; }

        const int e_nblk = e_rows * 2;
        const int m_nblk = (m_rows / 64) * KSPLIT;
        const int c_nblk = c_rows / 2;
        const int grid = c_nblk + m_nblk + e_nblk;
        if (grid == 0) continue;

        pipe_step<<<grid, 256, 0, stream>>>(
            user_idxs, item_idxs, user_nbt, item_nbt,
            us_bf, is_bf, ue_bf, ie_bf,
            xbuf[k & 1], k * CHUNK,
            xbuf[(k - 1) & 1], w1t, hpb[(k - 1) & 1], m_rows, m_nblk,
            hpb[k & 1], b1, W2, b2,
            out + (c_c > 0 ? (size_t)c_c * CHUNK : 0), c_rows, c_nblk);
    }
}

// Round 17
// 290.181 us; speedup vs baseline: 1.3175x; 1.3175x over previous
//
#include <hip/hip_runtime.h>
#include <hip/hip_bf16.h>
#include <math.h>

constexpr int KN  = 100;            // K (multi_factor * top_k)
constexpr int DE  = 64;             // embedding dim
constexpr int CAT = 2 * KN * DE;    // 12800
constexpr int HID = 128;
constexpr int KSPLIT = 4;
constexpr int KSEG = CAT / KSPLIT;  // 3200

typedef __bf16          bf16x8   __attribute__((ext_vector_type(8)));
typedef float           f32x4    __attribute__((ext_vector_type(4)));
typedef unsigned short  ushort8v __attribute__((ext_vector_type(8)));
typedef unsigned short  ushort4v __attribute__((ext_vector_type(4)));

static __device__ __forceinline__ unsigned short f2bf(float f) {
    __hip_bfloat16 h = __float2bfloat16(f);
    return *reinterpret_cast<unsigned short*>(&h);
}

static __device__ __forceinline__ bf16x8 mk_frag(ushort4v lo, ushort4v hi) {
    union { ushort8v u; bf16x8 b; } c;
    c.u = (ushort8v){ lo[0], lo[1], lo[2], lo[3], hi[0], hi[1], hi[2], hi[3] };
    return c.b;
}

// ---------------------------------------------------------------------------
// prep: 4 fp32->bf16 table conversions in one launch
// ---------------------------------------------------------------------------
__global__ __launch_bounds__(256) void cvt4(
    const float* __restrict__ a0, unsigned short* __restrict__ o0, int n0,
    const float* __restrict__ a1, unsigned short* __restrict__ o1, int n1,
    const float* __restrict__ a2, unsigned short* __restrict__ o2, int n2,
    const float* __restrict__ a3, unsigned short* __restrict__ o3, int n3)
{
    const float* in; unsigned short* out; int n4;
    switch (blockIdx.y) {
        case 0:  in = a0; out = o0; n4 = n0; break;
        case 1:  in = a1; out = o1; n4 = n1; break;
        case 2:  in = a2; out = o2; n4 = n2; break;
        default: in = a3; out = o3; n4 = n3; break;
    }
    for (int i = blockIdx.x * 256 + threadIdx.x; i < n4; i += gridDim.x * 256) {
        float4 v = ((const float4*)in)[i];
        ushort4v o = { f2bf(v.x), f2bf(v.y), f2bf(v.z), f2bf(v.w) };
        ((ushort4v*)out)[i] = o;
    }
}

// ---------------------------------------------------------------------------
// prep: w1t[n][k] = bf16(W1[k][n])
// ---------------------------------------------------------------------------
__global__ __launch_bounds__(256) void prep_w1t(
    const float* __restrict__ W1, unsigned short* __restrict__ w1t)
{
    __shared__ unsigned short T[HID][72];
    const int t  = threadIdx.x;
    const int k0 = blockIdx.x * 64;

    for (int idx = t; idx < 64 * HID; idx += 256) {
        int kk = idx >> 7, n = idx & 127;
        T[n][kk] = f2bf(W1[(size_t)(k0 + kk) * HID + n]);
    }
    __syncthreads();
    for (int idx = t; idx < HID * 16; idx += 256) {
        int n = idx >> 4, c4 = idx & 15;
        *(ushort4v*)&w1t[(size_t)n * CAT + k0 + c4 * 4] =
            *(const ushort4v*)&T[n][c4 * 4];
    }
}

// ---------------------------------------------------------------------------
// Kernel 1 (r15-proven, unchanged): launched ONCE over the full batch so the
// gather tables are warmed into L3 exactly once (FETCH/dispatch is ~row-count
// invariant per r16's measurement).
// ---------------------------------------------------------------------------
__global__ __launch_bounds__(256) void einsum_mfma(
    const int* __restrict__ u_idx, const int* __restrict__ i_idx,
    const int* __restrict__ u_nbt, const int* __restrict__ i_nbt,
    const unsigned short* __restrict__ u_scr, const unsigned short* __restrict__ i_scr,
    const unsigned short* __restrict__ u_emb, const unsigned short* __restrict__ i_emb,
    unsigned short* __restrict__ xb, int b0)
{
    __shared__ __align__(16) unsigned short ET[64][136];
    __shared__ int nb[KN];

    const int t    = threadIdx.x;
    const int side = blockIdx.y;
    const int b    = b0 + blockIdx.x;

    const int*            idxs = side ? i_idx : u_idx;
    const int*            nbt  = side ? i_nbt : u_nbt;
    const unsigned short* scr  = side ? i_scr : u_scr;
    const unsigned short* emb  = side ? i_emb : u_emb;

    const ushort4v z4 = {0, 0, 0, 0};

    const int center = idxs[b];
    if (t < KN) nb[t] = nbt[(size_t)center * KN + t];

    for (int idx = t; idx < 64 * 7; idx += 256) {
        int r = idx / 7, c = idx - r * 7;
        *(ushort4v*)&ET[r][100 + c * 4] = z4;
    }
    __syncthreads();                           // nb ready

    for (int idx = t; idx < 25 * 16; idx += 256) {
        int d4 = idx / 25, j0 = idx - d4 * 25;
        ushort4v v0 = *(const ushort4v*)(emb + (size_t)nb[j0 * 4 + 0] * DE + d4 * 4);
        ushort4v v1 = *(const ushort4v*)(emb + (size_t)nb[j0 * 4 + 1] * DE + d4 * 4);
        ushort4v v2 = *(const ushort4v*)(emb + (size_t)nb[j0 * 4 + 2] * DE + d4 * 4);
        ushort4v v3 = *(const ushort4v*)(emb + (size_t)nb[j0 * 4 + 3] * DE + d4 * 4);
        ushort4v o0 = { v0[0], v1[0], v2[0], v3[0] };
        ushort4v o1 = { v0[1], v1[1], v2[1], v3[1] };
        ushort4v o2 = { v0[2], v1[2], v2[2], v3[2] };
        ushort4v o3 = { v0[3], v1[3], v2[3], v3[3] };
        *(ushort4v*)&ET[d4 * 4 + 0][j0 * 4] = o0;
        *(ushort4v*)&ET[d4 * 4 + 1][j0 * 4] = o1;
        *(ushort4v*)&ET[d4 * 4 + 2][j0 * 4] = o2;
        *(ushort4v*)&ET[d4 * 4 + 3][j0 * 4] = o3;
    }
    __syncthreads();

    const int w  = t >> 6;
    const int l  = t & 63;
    const int cl = l & 15;
    const int rg = l >> 4;

    const unsigned short* srow[7];
    #pragma unroll
    for (int mt = 0; mt < 7; ++mt) {
        int kr = mt * 16 + cl;
        if (kr > KN - 1) kr = KN - 1;
        srow[mt] = scr + (size_t)nb[kr] * KN;
    }

    f32x4 acc[7];
    #pragma unroll
    for (int m = 0; m < 7; ++m) acc[m] = (f32x4){0.f, 0.f, 0.f, 0.f};

    #pragma unroll
    for (int ks = 0; ks < 4; ++ks) {
        const int k0 = ks * 32 + rg * 8;
        bf16x8 bfrag = *(const bf16x8*)&ET[w * 16 + cl][k0];
        #pragma unroll
        for (int mt = 0; mt < 7; ++mt) {
            ushort4v lo, hi;
            if (ks < 3) {
                lo = *(const ushort4v*)(srow[mt] + k0);
                hi = *(const ushort4v*)(srow[mt] + k0 + 4);
            } else if (rg == 0) {
                lo = *(const ushort4v*)(srow[mt] + 96);
                hi = z4;
            } else {
                lo = z4; hi = z4;
            }
            bf16x8 afrag = mk_frag(lo, hi);
            acc[mt] = __builtin_amdgcn_mfma_f32_16x16x32_bf16(afrag, bfrag, acc[mt], 0, 0, 0);
        }
    }
    __syncthreads();

    unsigned short* X = &ET[0][0];
    #pragma unroll
    for (int mt = 0; mt < 7; ++mt) {
        #pragma unroll
        for (int rr = 0; rr < 4; ++rr) {
            int k = mt * 16 + rg * 4 + rr;
            if (k < KN) X[k * 72 + w * 16 + cl] = f2bf(acc[mt][rr]);
        }
    }
    __syncthreads();

    unsigned short* xr = xb + (size_t)blockIdx.x * CAT + side * (KN * DE);
    for (int idx = t; idx < KN * 8; idx += 256) {
        int r = idx >> 3, c8 = idx & 7;
        __builtin_nontemporal_store(*(const ushort8v*)&X[r * 72 + c8 * 8],
                                    (ushort8v*)&xr[r * DE + c8 * 8]);
    }
}

// ---------------------------------------------------------------------------
// Kernel 2 (r13-proven config): full-batch K-split MLP h-partials.
// Grid (B/64, 4) = 512 blocks = 2 blocks/CU (LDS 55KB).  Block = 64 rows x
// 128 cols x K-seg 3200 (50 BK=64 dbuf steps).  nt xb-loads / hp-stores.
// ---------------------------------------------------------------------------
__global__ __launch_bounds__(256) void mlp_kpart(
    const unsigned short* __restrict__ xb, const unsigned short* __restrict__ w1t,
    float* __restrict__ hp, int Btot)
{
    __shared__ unsigned short A[2][64][72];    // 18.4 KB
    __shared__ unsigned short Bt[2][HID][72];  // 36.9 KB

    const int t  = threadIdx.x;
    const int w  = t >> 6;
    const int l  = t & 63;
    const int cl = l & 15;
    const int rg = l >> 4;
    const int row0  = blockIdx.x * 64;
    const int q     = blockIdx.y;
    const int kbase = q * KSEG;

    auto stage = [&](int buf, int kb) {
        #pragma unroll
        for (int i = 0; i < 2; ++i) {
            int c = t + i * 256;
            int r = c >> 3, c8 = c & 7;
            *(ushort8v*)&A[buf][r][c8 * 8] = __builtin_nontemporal_load(
                (const ushort8v*)&xb[(size_t)(row0 + r) * CAT + kbase + kb + c8 * 8]);
        }
        #pragma unroll
        for (int i = 0; i < 4; ++i) {
            int c = t + i * 256;
            int n = c >> 3, c8 = c & 7;
            *(ushort8v*)&Bt[buf][n][c8 * 8] =
                *(const ushort8v*)&w1t[(size_t)n * CAT + kbase + kb + c8 * 8];
        }
    };

    f32x4 acc[4][2];
    #pragma unroll
    for (int mt = 0; mt < 4; ++mt)
        #pragma unroll
        for (int nt = 0; nt < 2; ++nt)
            acc[mt][nt] = (f32x4){0.f, 0.f, 0.f, 0.f};

    stage(0, 0);
    __syncthreads();

    constexpr int NS = KSEG / 64;   // 50
    for (int s = 0; s < NS; ++s) {
        const int cur = s & 1;
        if (s + 1 < NS) stage(cur ^ 1, (s + 1) * 64);   // issue loads FIRST
        #pragma unroll
        for (int ks = 0; ks < 2; ++ks) {
            const int kcol = ks * 32 + rg * 8;
            bf16x8 bv0 = *(const bf16x8*)&Bt[cur][w * 32 + cl][kcol];
            bf16x8 bv1 = *(const bf16x8*)&Bt[cur][w * 32 + 16 + cl][kcol];
            #pragma unroll
            for (int mt = 0; mt < 4; ++mt) {
                bf16x8 a = *(const bf16x8*)&A[cur][mt * 16 + cl][kcol];
                acc[mt][0] = __builtin_amdgcn_mfma_f32_16x16x32_bf16(a, bv0, acc[mt][0], 0, 0, 0);
                acc[mt][1] = __builtin_amdgcn_mfma_f32_16x16x32_bf16(a, bv1, acc[mt][1], 0, 0, 0);
            }
        }
        __syncthreads();
    }

    #pragma unroll
    for (int mt = 0; mt < 4; ++mt) {
        #pragma unroll
        for (int nt = 0; nt < 2; ++nt) {
            #pragma unroll
            for (int r = 0; r < 4; ++r) {
                size_t row = (size_t)row0 + mt * 16 + rg * 4 + r;
                __builtin_nontemporal_store(acc[mt][nt][r],
                    &hp[((size_t)q * Btot + row) * HID + w * 32 + nt * 16 + cl]);
            }
        }
    }
}

// ---------------------------------------------------------------------------
// combine: h = relu(sum_{q<4} hp + b1); o = relu(h.W2 + b2); sigmoid.
// Fixed-order sum -> deterministic, same accumulation order as r13.
// ---------------------------------------------------------------------------
__global__ __launch_bounds__(256) void combine_sig(
    const float* __restrict__ hp, const float* __restrict__ b1,
    const float* __restrict__ W2, const float* __restrict__ b2,
    float* __restrict__ out, int Btot)
{
    __shared__ float red[4];
    const int t    = threadIdx.x;
    const int w    = t >> 6;
    const int l    = t & 63;
    const int rsel = w >> 1;
    const int col  = (w & 1) * 64 + l;
    const size_t row = (size_t)blockIdx.x * 2 + rsel;
    const size_t qs  = (size_t)Btot * HID;

    const float* hpr = hp + row * HID + col;
    float v = b1[col];
    #pragma unroll
    for (int j = 0; j < KSPLIT; ++j)
        v += __builtin_nontemporal_load(hpr + j * qs);
    float p = fmaxf(v, 0.f) * W2[col];
    p += __shfl_xor(p, 1,  64);
    p += __shfl_xor(p, 2,  64);
    p += __shfl_xor(p, 4,  64);
    p += __shfl_xor(p, 8,  64);
    p += __shfl_xor(p, 16, 64);
    p += __shfl_xor(p, 32, 64);
    if (l == 0) red[w] = p;
    __syncthreads();
    if (t < 2) {
        float o = red[2 * t] + red[2 * t + 1] + b2[0];
        o = fmaxf(o, 0.f);
        out[blockIdx.x * 2 + t] = 1.f / (1.f + expf(-o));
    }
}

// ---------------------------------------------------------------------------
extern "C" void kernel_launch(void* const* d_in, const int* in_sizes, int n_in,
                              void* d_out, int out_size, void* d_ws, size_t ws_size,
                              hipStream_t stream)
{
    const int*   user_idxs = (const int*)d_in[0];
    const int*   item_idxs = (const int*)d_in[1];
    const int*   user_nbt  = (const int*)d_in[2];
    const int*   item_nbt  = (const int*)d_in[3];
    const float* user_scr  = (const float*)d_in[4];
    const float* item_scr  = (const float*)d_in[5];
    const float* user_emb  = (const float*)d_in[6];
    const float* item_emb  = (const float*)d_in[7];
    const float* W1        = (const float*)d_in[8];
    const float* b1        = (const float*)d_in[9];
    const float* W2        = (const float*)d_in[10];
    const float* b2        = (const float*)d_in[11];
    float*       out       = (float*)d_out;

    const int B = in_sizes[0];      // 8192

    // ws layout (r6/r11-proven 263 MB footprint): [w1t][tables][xb full].
    // hp (16.8 MB) ALIASES us_bf (20 MB): tables dead after the single
    // einsum dispatch; cvt4 rewrites them at the start of every replay.
    char* p = (char*)d_ws;
    unsigned short* w1t   = (unsigned short*)p;  p += (size_t)HID * CAT * 2;
    unsigned short* us_bf = (unsigned short*)p;  p += (size_t)in_sizes[4] * 2;
    unsigned short* is_bf = (unsigned short*)p;  p += (size_t)in_sizes[5] * 2;
    unsigned short* ue_bf = (unsigned short*)p;  p += (size_t)in_sizes[6] * 2;
    unsigned short* ie_bf = (unsigned short*)p;  p += (size_t)in_sizes[7] * 2;
    unsigned short* xb    = (unsigned short*)p;  // B*CAT*2 = 210 MB
    float*          hpb   = (float*)us_bf;       // alias (16.8 MB <= 20 MB)

    prep_w1t<<<CAT / 64, 256, 0, stream>>>(W1, w1t);
    cvt4<<<dim3(512, 4), 256, 0, stream>>>(
        user_scr, us_bf, in_sizes[4] / 4,
        item_scr, is_bf, in_sizes[5] / 4,
        user_emb, ue_bf, in_sizes[6] / 4,
        item_emb, ie_bf, in_sizes[7] / 4);

    // ONE einsum dispatch over the full batch: tables warm into L3 once
    einsum_mfma<<<dim3(B, 2), 256, 0, stream>>>(
        user_idxs, item_idxs, user_nbt, item_nbt,
        us_bf, is_bf, ue_bf, ie_bf, xb, 0);

    // full-batch MLP partials (2 blocks/CU) + combine
    mlp_kpart<<<dim3(B / 64, KSPLIT), 256, 0, stream>>>(xb, w1t, hpb, B);
    combine_sig<<<B / 2, 256, 0, stream>>>(hpb, b1, W2, b2, out, B);
}